// Round 7
// baseline (195.077 us; speedup 1.0000x reference)
//
#include <hip/hip_runtime.h>
#include <hip/hip_bf16.h>
#include <math.h>

// B=2, T=2048, C=1024, H=16, D=64
typedef __attribute__((ext_vector_type(8))) short s8v;    // 8 bf16
typedef __attribute__((ext_vector_type(4))) float f4v;    // 4 fp32
typedef __attribute__((ext_vector_type(16))) float f16v;  // 16 fp32 (32x32 C/D)
typedef unsigned short ush;
typedef unsigned int u32;

#define QSCALE 0.180336880f   /* 0.125 * log2(e): S emerges in log2 domain */

static __device__ __forceinline__ ush f2bf(float f) {
    u32 x = __builtin_bit_cast(u32, f);
    return (ush)((x + 0x7fffu + ((x >> 16) & 1u)) >> 16);
}
static __device__ __forceinline__ u32 bfpack(float lo, float hi) {
    u32 a = __builtin_bit_cast(u32, lo) + 0x8000u;
    u32 b = __builtin_bit_cast(u32, hi) + 0x8000u;
    return __builtin_amdgcn_perm(b, a, 0x07060302);
}
static __device__ __forceinline__ void gl_lds16(const void* g, void* l) {
    __builtin_amdgcn_global_load_lds(
        (const __attribute__((address_space(1))) u32*)g,
        (__attribute__((address_space(3))) u32*)l, 16, 0, 0);
}
#if __has_builtin(__builtin_amdgcn_exp2f)
#define EXP2F(x) __builtin_amdgcn_exp2f(x)
#else
#define EXP2F(x) exp2f(x)
#endif

// ---------------------------------------------------------------------------
// Prep (fused): blocks [0,512): Wt[n][k] = bf16(W[k][n]);
//               blocks [512,1536): Vt[b][h][d][t] = bf16(x_v[b][t][h*64+d]).
// ---------------------------------------------------------------------------
__global__ __launch_bounds__(256) void prep_kernel(
    const float* __restrict__ W, const float* __restrict__ XV,
    ush* __restrict__ Wt, ush* __restrict__ Vt)
{
    __shared__ float Ts[64][68];
    const int tid = threadIdx.x;
    const int bid = blockIdx.x;
    if (bid < 512) {
        const int n0 = (bid & 31) * 64, k0 = (bid >> 5) * 64;
        #pragma unroll
        for (int p = 0; p < 4; ++p) {
            const int idx = p * 256 + tid;
            const int kr = idx >> 4, nc4 = idx & 15;
            float4 v = *(const float4*)(W + (size_t)(k0 + kr) * 2048 + n0 + nc4 * 4);
            Ts[kr][nc4 * 4 + 0] = v.x; Ts[kr][nc4 * 4 + 1] = v.y;
            Ts[kr][nc4 * 4 + 2] = v.z; Ts[kr][nc4 * 4 + 3] = v.w;
        }
        __syncthreads();
        const int n = tid >> 2, kb = (tid & 3) * 16;
        #pragma unroll
        for (int p = 0; p < 4; ++p) {
            const int k = kb + p * 4;
            ushort4 o;
            o.x = f2bf(Ts[k + 0][n]); o.y = f2bf(Ts[k + 1][n]);
            o.z = f2bf(Ts[k + 2][n]); o.w = f2bf(Ts[k + 3][n]);
            *(ushort4*)(Wt + (size_t)(n0 + n) * 1024 + k0 + k) = o;
        }
    } else {
        const int id = bid - 512;
        const int t0 = (id & 31) * 64, bh = id >> 5;
        const int b = bh >> 4, h = bh & 15;
        #pragma unroll
        for (int p = 0; p < 4; ++p) {
            const int idx = p * 256 + tid;
            const int tr = idx >> 4, dc4 = idx & 15;
            float4 v = *(const float4*)(XV + (size_t)(b * 2048 + t0 + tr) * 1024
                                        + h * 64 + dc4 * 4);
            Ts[tr][dc4 * 4 + 0] = v.x; Ts[tr][dc4 * 4 + 1] = v.y;
            Ts[tr][dc4 * 4 + 2] = v.z; Ts[tr][dc4 * 4 + 3] = v.w;
        }
        __syncthreads();
        const int d = tid >> 2, tb = (tid & 3) * 16;
        #pragma unroll
        for (int p = 0; p < 4; ++p) {
            const int tq = tb + p * 4;
            ushort4 o;
            o.x = f2bf(Ts[tq + 0][d]); o.y = f2bf(Ts[tq + 1][d]);
            o.z = f2bf(Ts[tq + 2][d]); o.w = f2bf(Ts[tq + 3][d]);
            *(ushort4*)(Vt + (size_t)((b * 16 + h) * 64 + d) * 2048 + t0 + tq) = o;
        }
    }
}

// ---------------------------------------------------------------------------
// MFMA GEMM: C = bf16(X) @ Wt^T + bias.  128x128 tile, BK=32.
//   A: fp32 X -> inline bf16 convert -> LDS (stride 40, b128-aligned).
//   B: bf16 Wt via global_load_lds width-16 (unpadded stride 32).
//   Epilogue: +bias; Q *= 0.125*log2e; scatter to [b][h][t][d].
// ---------------------------------------------------------------------------
__global__ __launch_bounds__(256) void gemm_kernel(
    const float* __restrict__ X, const ush* __restrict__ Wt,
    const float* __restrict__ bias,
    ush* __restrict__ Qb, ush* __restrict__ Kb)
{
    __shared__ ush As[128 * 40];   // [m][k] stride 40 (80 B = 5x16 B)
    __shared__ ush Bs[128 * 32];   // [n][k] unpadded (DMA layout)

    const int tid = threadIdx.x;
    const int wid = tid >> 6, lane = tid & 63;
    const int quad = lane >> 4, l15 = lane & 15;
    const int wm = wid >> 1, wn = wid & 1;
    const int m0 = blockIdx.y * 128, n0 = blockIdx.x * 128;

    const int arow = tid >> 1;          // 0..127
    const int akc = (tid & 1) * 16;     // 0 or 16
    const int brow = lane >> 2;
    const int bkk = (lane & 3) * 8;
    const size_t brow_g = (size_t)(n0 + wid * 32 + brow);
    ush* BsW = &Bs[wid * 1024];

    f4v acc[4][4];
    #pragma unroll
    for (int i = 0; i < 4; ++i)
        #pragma unroll
        for (int j = 0; j < 4; ++j) acc[i][j] = (f4v){0.f, 0.f, 0.f, 0.f};

    for (int k0 = 0; k0 < 1024; k0 += 32) {
        gl_lds16(Wt + brow_g * 1024 + k0 + bkk, BsW);
        gl_lds16(Wt + (brow_g + 16) * 1024 + k0 + bkk, BsW + 512);
        {
            const float* xp = X + (size_t)(m0 + arow) * 1024 + k0 + akc;
            float4 f0 = ((const float4*)xp)[0];
            float4 f1 = ((const float4*)xp)[1];
            float4 f2 = ((const float4*)xp)[2];
            float4 f3 = ((const float4*)xp)[3];
            uint4 w0, w1;
            w0.x = bfpack(f0.x, f0.y); w0.y = bfpack(f0.z, f0.w);
            w0.z = bfpack(f1.x, f1.y); w0.w = bfpack(f1.z, f1.w);
            w1.x = bfpack(f2.x, f2.y); w1.y = bfpack(f2.z, f2.w);
            w1.z = bfpack(f3.x, f3.y); w1.w = bfpack(f3.z, f3.w);
            *(uint4*)&As[arow * 40 + akc] = w0;
            *(uint4*)&As[arow * 40 + akc + 8] = w1;
        }
        __syncthreads();

        s8v a[4], bf[4];
        #pragma unroll
        for (int i = 0; i < 4; ++i)
            a[i] = *(const s8v*)&As[(wm * 64 + i * 16 + l15) * 40 + quad * 8];
        #pragma unroll
        for (int j = 0; j < 4; ++j)
            bf[j] = *(const s8v*)&Bs[(wn * 64 + j * 16 + l15) * 32 + quad * 8];
        #pragma unroll
        for (int i = 0; i < 4; ++i)
            #pragma unroll
            for (int j = 0; j < 4; ++j)
                acc[i][j] = __builtin_amdgcn_mfma_f32_16x16x32_bf16(
                    a[i], bf[j], acc[i][j], 0, 0, 0);
        __syncthreads();
    }

    #pragma unroll
    for (int j = 0; j < 4; ++j) {
        const int n = n0 + wn * 64 + j * 16 + l15;
        const float bv = bias[n];
        const bool is_k = n >= 1024;
        const int nn = n & 1023;
        const int h = nn >> 6, d = nn & 63;
        ush* dst = is_k ? Kb : Qb;
        #pragma unroll
        for (int i = 0; i < 4; ++i) {
            const int mrow = m0 + wm * 64 + i * 16 + quad * 4;
            #pragma unroll
            for (int r = 0; r < 4; ++r) {
                const int m = mrow + r;
                const int b = m >> 11, t = m & 2047;
                float val = acc[i][j][r] + bv;
                if (!is_k) val *= QSCALE;
                dst[(size_t)((b * 16 + h) * 2048 + t) * 64 + d] = f2bf(val);
            }
        }
    }
}

// ---------------------------------------------------------------------------
// MFMA causal flash attention: 64 q-rows/block, 128 thr = 2 waves x 32q.
//   32x32x16 MFMA, S^T form (lane column q = lane&31). P never touches LDS:
//   bf16-packed S^T registers are swapped across lane halves (shfl_xor 32)
//   into the PV B-fragment. K/V double-buffered via swizzled global_load_lds.
//   LDS exactly 32 KB -> grid 1024 fully co-resident, 4 blocks/CU.
// ---------------------------------------------------------------------------
__global__ __launch_bounds__(128) void attn_kernel(
    const ush* __restrict__ Qb, const ush* __restrict__ Kb,
    const ush* __restrict__ Vt, float* __restrict__ Y)
{
    __shared__ ush SMEM[16384];            // 32 KB
    ush* Kbuf = SMEM;                      // [buf*4096 + row*64 + elem]
    ush* Vbuf = SMEM + 8192;               // [buf*4096 + drow*64 + elem]

    const int tid = threadIdx.x;
    const int w = tid >> 6, lane = tid & 63;
    const int l31 = lane & 31, hi = lane >> 5;

    // qt interleaved hi/lo across consecutive blocks (XCD balance)
    const int idx = blockIdx.x;
    const int bh = idx >> 5, j = idx & 31;
    const int qt = (j & 1) ? (j >> 1) : 31 - (j >> 1);
    const int b = bh >> 4, h = bh & 15;
    const int q0 = qt * 64;

    const ush* Qg = Qb + (size_t)bh * 2048 * 64;
    const ush* Kg = Kb + (size_t)bh * 2048 * 64;
    const ush* Vg = Vt + (size_t)bh * 64 * 2048;

    // ---- swizzled DMA staging: chunk c of row r -> LDS chunk c^(r&7)
    const int r8 = lane >> 3;                  // 0..7
    const int g8 = ((lane & 7) ^ r8) * 8;      // swizzled elem offset
    auto stage = [&](int kt, int buf) {
        const int k0e = kt * 64;
        #pragma unroll
        for (int i = 0; i < 4; ++i) {
            const int rowb = w * 32 + i * 8;
            gl_lds16(Kg + (size_t)(k0e + rowb + r8) * 64 + g8,
                     &Kbuf[buf * 4096 + rowb * 64]);
            gl_lds16(Vg + (size_t)(rowb + r8) * 2048 + k0e + g8,
                     &Vbuf[buf * 4096 + rowb * 64]);
        }
    };

    // ---- stage tile 0 (DMA) + Q rows (regs->LDS, temp in Vbuf[1])
    stage(0, 0);
    ush* Qtmp = SMEM + 12288 + w * 2048;    // 32 rows x 64 d per wave
    {
        // FIX (R6 bug): cover FULL 64-elem rows. 8 lanes/row, 4 rounds.
        const int c8 = lane & 7;
        #pragma unroll
        for (int p = 0; p < 4; ++p) {
            const int qrow = p * 8 + r8;      // 0..31
            uint4 v = *(const uint4*)(Qg + (size_t)(q0 + w * 32 + qrow) * 64 + c8 * 8);
            *(uint4*)&Qtmp[qrow * 64 + c8 * 8] = v;
        }
    }
    __syncthreads();
    s8v bq[4];
    #pragma unroll
    for (int s = 0; s < 4; ++s)
        bq[s] = *(const s8v*)&Qtmp[l31 * 64 + s * 16 + hi * 8];
    __syncthreads();   // bq reads done -> stage(1) may clobber Qtmp

    f16v acco0 = {}, acco1 = {};
    float mr = -INFINITY, lr = 0.f;
    const int qg = q0 + w * 32 + l31;          // lane's q row (global)

    for (int kt = 0; kt <= qt; ++kt) {
        const int buf = kt & 1;
        if (kt < qt) stage(kt + 1, buf ^ 1);

        // S^T = K Q^T : rows=keys (2 tiles of 32), col=q=l31
        f16v s0 = {}, s1 = {};
        #pragma unroll
        for (int s = 0; s < 4; ++s) {
            const int ch = (s << 1) + hi;
            const int row0 = l31, row1 = 32 + l31;
            s8v ak0 = *(const s8v*)&Kbuf[buf * 4096 + row0 * 64 + ((ch ^ (row0 & 7)) << 3)];
            s8v ak1 = *(const s8v*)&Kbuf[buf * 4096 + row1 * 64 + ((ch ^ (row1 & 7)) << 3)];
            s0 = __builtin_amdgcn_mfma_f32_32x32x16_bf16(ak0, bq[s], s0, 0, 0, 0);
            s1 = __builtin_amdgcn_mfma_f32_32x32x16_bf16(ak1, bq[s], s1, 0, 0, 0);
        }

        // causal mask (diag tile only) + running max
        float mloc = -INFINITY;
        if (kt == qt) {
            #pragma unroll
            for (int r = 0; r < 16; ++r) {
                const int keyb = kt * 64 + (r & 3) + 8 * (r >> 2) + 4 * hi;
                float v0 = (keyb > qg) ? -INFINITY : s0[r];
                float v1 = (keyb + 32 > qg) ? -INFINITY : s1[r];
                s0[r] = v0; s1[r] = v1;
                mloc = fmaxf(mloc, fmaxf(v0, v1));
            }
        } else {
            #pragma unroll
            for (int r = 0; r < 16; ++r)
                mloc = fmaxf(mloc, fmaxf(s0[r], s1[r]));
        }
        mloc = fmaxf(mloc, __shfl_xor(mloc, 32));
        const float mnew = fmaxf(mr, mloc);
        const float alpha = EXP2F(mr - mnew);
        mr = mnew;

        // exp2 + row sum + bf16 pack (pairs of consecutive keys)
        float ps = 0.f;
        u32 P0[8], P1[8];
        #pragma unroll
        for (int p = 0; p < 8; ++p) {
            float a0 = EXP2F(s0[2 * p] - mnew), b0 = EXP2F(s0[2 * p + 1] - mnew);
            float a1 = EXP2F(s1[2 * p] - mnew), b1 = EXP2F(s1[2 * p + 1] - mnew);
            ps += (a0 + b0) + (a1 + b1);
            P0[p] = bfpack(a0, b0); P1[p] = bfpack(a1, b1);
        }
        ps += __shfl_xor(ps, 32);
        lr = lr * alpha + ps;

        #pragma unroll
        for (int r = 0; r < 16; ++r) { acco0[r] *= alpha; acco1[r] *= alpha; }

        // O^T += V^T P^T.  B-frag(P^T) built in-register: lane half swap.
        //   pack p of tile t holds keys t*32 + (p&1)*2 + 8*(p>>1) + 4*hi (+0,1)
        #pragma unroll
        for (int t = 0; t < 2; ++t) {
            const u32* pt = t ? P1 : P0;
            #pragma unroll
            for (int ss = 0; ss < 2; ++ss) {
                const int b4 = ss * 4;
                const u32 x0 = __shfl_xor(pt[b4 + 0], 32);
                const u32 x1 = __shfl_xor(pt[b4 + 1], 32);
                const u32 x2 = __shfl_xor(pt[b4 + 2], 32);
                const u32 x3 = __shfl_xor(pt[b4 + 3], 32);
                uint4 fr;
                fr.x = hi ? x2 : pt[b4 + 0];
                fr.y = hi ? x3 : pt[b4 + 1];
                fr.z = hi ? pt[b4 + 2] : x0;
                fr.w = hi ? pt[b4 + 3] : x1;
                const s8v pf = __builtin_bit_cast(s8v, fr);
                const int sg = t * 2 + ss, ch = (sg << 1) + hi;
                const int row0 = l31, row1 = 32 + l31;
                s8v av0 = *(const s8v*)&Vbuf[buf * 4096 + row0 * 64 + ((ch ^ (row0 & 7)) << 3)];
                s8v av1 = *(const s8v*)&Vbuf[buf * 4096 + row1 * 64 + ((ch ^ (row1 & 7)) << 3)];
                acco0 = __builtin_amdgcn_mfma_f32_32x32x16_bf16(av0, pf, acco0, 0, 0, 0);
                acco1 = __builtin_amdgcn_mfma_f32_32x32x16_bf16(av1, pf, acco1, 0, 0, 0);
            }
        }

        __syncthreads();   // waves done with buf; next-tile DMA drained here
    }

    // ---- epilogue: per-wave LDS transpose (overlay K/V) -> coalesced stores
    float* LTw = (float*)SMEM + w * (32 * 68);
    const float inv = 1.0f / lr;
    #pragma unroll
    for (int r = 0; r < 16; ++r) {
        const int d = (r & 3) + 8 * (r >> 2) + 4 * hi;
        LTw[l31 * 68 + d] = acco0[r] * inv;
        LTw[l31 * 68 + 32 + d] = acco1[r] * inv;
    }
    const int qr2 = lane >> 4, chk = lane & 15;
    #pragma unroll
    for (int p = 0; p < 8; ++p) {
        const int qrow = p * 4 + qr2;
        f4v v = *(const f4v*)&LTw[qrow * 68 + chk * 4];
        *(float4*)(Y + (size_t)(b * 2048 + q0 + w * 32 + qrow) * 1024
                   + h * 64 + chk * 4) = (float4){v[0], v[1], v[2], v[3]};
    }
}

// ---------------------------------------------------------------------------
extern "C" void kernel_launch(void* const* d_in, const int* in_sizes, int n_in,
                              void* d_out, int out_size, void* d_ws,
                              size_t ws_size, hipStream_t stream)
{
    const float* x_qk = (const float*)d_in[0];
    const float* x_v  = (const float*)d_in[1];
    const float* W    = (const float*)d_in[2];
    const float* bias = (const float*)d_in[3];
    float* out = (float*)d_out;

    unsigned char* ws = (unsigned char*)d_ws;
    ush* Wt = (ush*)(ws);                  // 4 MB  [0,4M)
    ush* Vt = (ush*)(ws + (4u << 20));     // 8 MB  [4M,12M)
    ush* Qb = (ush*)(ws + (12u << 20));    // 8 MB  [12M,20M)
    ush* Kb = (ush*)(ws + (20u << 20));    // 8 MB  [20M,28M)

    prep_kernel<<<1536, 256, 0, stream>>>(W, x_v, Wt, Vt);
    gemm_kernel<<<dim3(16, 32), 256, 0, stream>>>(x_qk, Wt, bias, Qb, Kb);
    attn_kernel<<<1024, 128, 0, stream>>>(Qb, Kb, Vt, out);
}

// Round 8
// 180.713 us; speedup vs baseline: 1.0795x; 1.0795x over previous
//
#include <hip/hip_runtime.h>
#include <hip/hip_bf16.h>
#include <math.h>

// B=2, T=2048, C=1024, H=16, D=64
typedef __attribute__((ext_vector_type(8))) short s8v;    // 8 bf16
typedef __attribute__((ext_vector_type(4))) float f4v;    // 4 fp32
typedef __attribute__((ext_vector_type(16))) float f16v;  // 16 fp32 (32x32 C/D)
typedef unsigned short ush;
typedef unsigned int u32;

#define QSCALE 0.180336880f   /* 0.125 * log2(e): S emerges in log2 domain */

static __device__ __forceinline__ ush f2bf(float f) {
    u32 x = __builtin_bit_cast(u32, f);
    return (ush)((x + 0x7fffu + ((x >> 16) & 1u)) >> 16);
}
static __device__ __forceinline__ u32 bfpack(float lo, float hi) {
    u32 a = __builtin_bit_cast(u32, lo) + 0x8000u;
    u32 b = __builtin_bit_cast(u32, hi) + 0x8000u;
    return __builtin_amdgcn_perm(b, a, 0x07060302);
}
static __device__ __forceinline__ void gl_lds16(const void* g, void* l) {
    __builtin_amdgcn_global_load_lds(
        (const __attribute__((address_space(1))) u32*)g,
        (__attribute__((address_space(3))) u32*)l, 16, 0, 0);
}
#if __has_builtin(__builtin_amdgcn_exp2f)
#define EXP2F(x) __builtin_amdgcn_exp2f(x)
#else
#define EXP2F(x) exp2f(x)
#endif

// ---------------------------------------------------------------------------
// Prep (fused): blocks [0,512): Wt[n][k] = bf16(W[k][n]);
//               blocks [512,1536): Vt[b][h][d][t] = bf16(x_v[b][t][h*64+d]).
// ---------------------------------------------------------------------------
__global__ __launch_bounds__(256) void prep_kernel(
    const float* __restrict__ W, const float* __restrict__ XV,
    ush* __restrict__ Wt, ush* __restrict__ Vt)
{
    __shared__ float Ts[64][68];
    const int tid = threadIdx.x;
    const int bid = blockIdx.x;
    if (bid < 512) {
        const int n0 = (bid & 31) * 64, k0 = (bid >> 5) * 64;
        #pragma unroll
        for (int p = 0; p < 4; ++p) {
            const int idx = p * 256 + tid;
            const int kr = idx >> 4, nc4 = idx & 15;
            float4 v = *(const float4*)(W + (size_t)(k0 + kr) * 2048 + n0 + nc4 * 4);
            Ts[kr][nc4 * 4 + 0] = v.x; Ts[kr][nc4 * 4 + 1] = v.y;
            Ts[kr][nc4 * 4 + 2] = v.z; Ts[kr][nc4 * 4 + 3] = v.w;
        }
        __syncthreads();
        const int n = tid >> 2, kb = (tid & 3) * 16;
        #pragma unroll
        for (int p = 0; p < 4; ++p) {
            const int k = kb + p * 4;
            ushort4 o;
            o.x = f2bf(Ts[k + 0][n]); o.y = f2bf(Ts[k + 1][n]);
            o.z = f2bf(Ts[k + 2][n]); o.w = f2bf(Ts[k + 3][n]);
            *(ushort4*)(Wt + (size_t)(n0 + n) * 1024 + k0 + k) = o;
        }
    } else {
        const int id = bid - 512;
        const int t0 = (id & 31) * 64, bh = id >> 5;
        const int b = bh >> 4, h = bh & 15;
        #pragma unroll
        for (int p = 0; p < 4; ++p) {
            const int idx = p * 256 + tid;
            const int tr = idx >> 4, dc4 = idx & 15;
            float4 v = *(const float4*)(XV + (size_t)(b * 2048 + t0 + tr) * 1024
                                        + h * 64 + dc4 * 4);
            Ts[tr][dc4 * 4 + 0] = v.x; Ts[tr][dc4 * 4 + 1] = v.y;
            Ts[tr][dc4 * 4 + 2] = v.z; Ts[tr][dc4 * 4 + 3] = v.w;
        }
        __syncthreads();
        const int d = tid >> 2, tb = (tid & 3) * 16;
        #pragma unroll
        for (int p = 0; p < 4; ++p) {
            const int tq = tb + p * 4;
            ushort4 o;
            o.x = f2bf(Ts[tq + 0][d]); o.y = f2bf(Ts[tq + 1][d]);
            o.z = f2bf(Ts[tq + 2][d]); o.w = f2bf(Ts[tq + 3][d]);
            *(ushort4*)(Vt + (size_t)((b * 16 + h) * 64 + d) * 2048 + t0 + tq) = o;
        }
    }
}

// ---------------------------------------------------------------------------
// MFMA GEMM: C = bf16(X) @ Wt^T + bias.  128x128 tile, BK=64 (64 MFMA/barrier).
//   A: fp32 X -> inline bf16 convert -> LDS (stride 72, b128-aligned).
//   B: bf16 Wt via global_load_lds width-16 (unpadded stride 64).
//   Epilogue: +bias; Q *= 0.125*log2e; scatter to [b][h][t][d].
// ---------------------------------------------------------------------------
__global__ __launch_bounds__(256) void gemm_kernel(
    const float* __restrict__ X, const ush* __restrict__ Wt,
    const float* __restrict__ bias,
    ush* __restrict__ Qb, ush* __restrict__ Kb)
{
    __shared__ ush As[128 * 72];   // [m][k] stride 72 (144 B = 9x16 B)
    __shared__ ush Bs[128 * 64];   // [n][k] unpadded (DMA layout)

    const int tid = threadIdx.x;
    const int wid = tid >> 6, lane = tid & 63;
    const int quad = lane >> 4, l15 = lane & 15;
    const int wm = wid >> 1, wn = wid & 1;
    const int m0 = blockIdx.y * 128, n0 = blockIdx.x * 128;

    const int arow = tid >> 1;          // 0..127
    const int akc = (tid & 1) * 32;     // 0 or 32
    const int brow_l = lane >> 3;       // 0..7
    const int bkk = (lane & 7) * 8;     // elem offset within 64-k row

    f4v acc[4][4];
    #pragma unroll
    for (int i = 0; i < 4; ++i)
        #pragma unroll
        for (int j = 0; j < 4; ++j) acc[i][j] = (f4v){0.f, 0.f, 0.f, 0.f};

    for (int k0 = 0; k0 < 1024; k0 += 64) {
        // stage B: 128 rows x 64 k via DMA (4 instrs/wave, 8 rows each)
        #pragma unroll
        for (int i = 0; i < 4; ++i) {
            const int rowb = wid * 32 + i * 8;
            gl_lds16(Wt + (size_t)(n0 + rowb + brow_l) * 1024 + k0 + bkk,
                     &Bs[rowb * 64]);
        }
        // stage A: row arow, k [akc, akc+32) fp32 -> bf16
        {
            const float* xp = X + (size_t)(m0 + arow) * 1024 + k0 + akc;
            float4 f0 = ((const float4*)xp)[0];
            float4 f1 = ((const float4*)xp)[1];
            float4 f2 = ((const float4*)xp)[2];
            float4 f3 = ((const float4*)xp)[3];
            float4 f4 = ((const float4*)xp)[4];
            float4 f5 = ((const float4*)xp)[5];
            float4 f6 = ((const float4*)xp)[6];
            float4 f7 = ((const float4*)xp)[7];
            uint4 w0, w1;
            w0.x = bfpack(f0.x, f0.y); w0.y = bfpack(f0.z, f0.w);
            w0.z = bfpack(f1.x, f1.y); w0.w = bfpack(f1.z, f1.w);
            w1.x = bfpack(f2.x, f2.y); w1.y = bfpack(f2.z, f2.w);
            w1.z = bfpack(f3.x, f3.y); w1.w = bfpack(f3.z, f3.w);
            *(uint4*)&As[arow * 72 + akc] = w0;
            *(uint4*)&As[arow * 72 + akc + 8] = w1;
            w0.x = bfpack(f4.x, f4.y); w0.y = bfpack(f4.z, f4.w);
            w0.z = bfpack(f5.x, f5.y); w0.w = bfpack(f5.z, f5.w);
            w1.x = bfpack(f6.x, f6.y); w1.y = bfpack(f6.z, f6.w);
            w1.z = bfpack(f7.x, f7.y); w1.w = bfpack(f7.z, f7.w);
            *(uint4*)&As[arow * 72 + akc + 16] = w0;
            *(uint4*)&As[arow * 72 + akc + 24] = w1;
        }
        __syncthreads();

        #pragma unroll
        for (int ks = 0; ks < 2; ++ks) {
            s8v a[4], bf[4];
            #pragma unroll
            for (int i = 0; i < 4; ++i)
                a[i] = *(const s8v*)&As[(wm * 64 + i * 16 + l15) * 72 + ks * 32 + quad * 8];
            #pragma unroll
            for (int j = 0; j < 4; ++j)
                bf[j] = *(const s8v*)&Bs[(wn * 64 + j * 16 + l15) * 64 + ks * 32 + quad * 8];
            #pragma unroll
            for (int i = 0; i < 4; ++i)
                #pragma unroll
                for (int j = 0; j < 4; ++j)
                    acc[i][j] = __builtin_amdgcn_mfma_f32_16x16x32_bf16(
                        a[i], bf[j], acc[i][j], 0, 0, 0);
        }
        __syncthreads();
    }

    #pragma unroll
    for (int j = 0; j < 4; ++j) {
        const int n = n0 + wn * 64 + j * 16 + l15;
        const float bv = bias[n];
        const bool is_k = n >= 1024;
        const int nn = n & 1023;
        const int h = nn >> 6, d = nn & 63;
        ush* dst = is_k ? Kb : Qb;
        #pragma unroll
        for (int i = 0; i < 4; ++i) {
            const int mrow = m0 + wm * 64 + i * 16 + quad * 4;
            #pragma unroll
            for (int r = 0; r < 4; ++r) {
                const int m = mrow + r;
                const int b = m >> 11, t = m & 2047;
                float val = acc[i][j][r] + bv;
                if (!is_k) val *= QSCALE;
                dst[(size_t)((b * 16 + h) * 2048 + t) * 64 + d] = f2bf(val);
            }
        }
    }
}

// ---------------------------------------------------------------------------
// MFMA causal flash attention: 64 q-rows/block, 128 thr = 2 waves x 32q.
//   32x32x16 MFMA, S^T form (lane column q = lane&31). P stays in registers
//   (shfl_xor-32 half swap builds the PV B-frag). K/V double-buffered via
//   swizzled global_load_lds. LDS 32 KB -> 4+ blocks/CU.
//   qt schedule: the 4 blocks sharing a CU slot (idx, idx+256, idx+512,
//   idx+768) get qt {2s, 31-2s, 2s+1, 30-2s} -> per-slot work constant (66).
// ---------------------------------------------------------------------------
__global__ __launch_bounds__(128) void attn_kernel(
    const ush* __restrict__ Qb, const ush* __restrict__ Kb,
    const ush* __restrict__ Vt, float* __restrict__ Y)
{
    __shared__ ush SMEM[16384];            // 32 KB
    ush* Kbuf = SMEM;                      // [buf*4096 + row*64 + elem]
    ush* Vbuf = SMEM + 8192;               // [buf*4096 + drow*64 + elem]

    const int tid = threadIdx.x;
    const int w = tid >> 6, lane = tid & 63;
    const int l31 = lane & 31, hi = lane >> 5;

    // CU-balanced qt schedule (see header comment)
    const int idx = blockIdx.x;
    const int rr = idx >> 8, ii = idx & 255;
    const int bh = ii >> 3, s_ = ii & 7;
    const int qt = (rr & 1) ? (31 - (2 * s_ + (rr >> 1))) : (2 * s_ + (rr >> 1));
    const int b = bh >> 4, h = bh & 15;
    const int q0 = qt * 64;

    const ush* Qg = Qb + (size_t)bh * 2048 * 64;
    const ush* Kg = Kb + (size_t)bh * 2048 * 64;
    const ush* Vg = Vt + (size_t)bh * 64 * 2048;

    // ---- swizzled DMA staging: chunk c of row r -> LDS chunk c^(r&7)
    const int r8 = lane >> 3;                  // 0..7
    const int g8 = ((lane & 7) ^ r8) * 8;      // swizzled elem offset
    auto stage = [&](int kt, int buf) {
        const int k0e = kt * 64;
        #pragma unroll
        for (int i = 0; i < 4; ++i) {
            const int rowb = w * 32 + i * 8;
            gl_lds16(Kg + (size_t)(k0e + rowb + r8) * 64 + g8,
                     &Kbuf[buf * 4096 + rowb * 64]);
            gl_lds16(Vg + (size_t)(rowb + r8) * 2048 + k0e + g8,
                     &Vbuf[buf * 4096 + rowb * 64]);
        }
    };

    // ---- stage tile 0 (DMA) + Q rows (regs->LDS, temp in Vbuf[1])
    stage(0, 0);
    ush* Qtmp = SMEM + 12288 + w * 2048;    // 32 rows x 64 d per wave
    {
        const int c8 = lane & 7;
        #pragma unroll
        for (int p = 0; p < 4; ++p) {
            const int qrow = p * 8 + r8;      // 0..31
            uint4 v = *(const uint4*)(Qg + (size_t)(q0 + w * 32 + qrow) * 64 + c8 * 8);
            *(uint4*)&Qtmp[qrow * 64 + c8 * 8] = v;
        }
    }
    __syncthreads();
    s8v bq[4];
    #pragma unroll
    for (int s = 0; s < 4; ++s)
        bq[s] = *(const s8v*)&Qtmp[l31 * 64 + s * 16 + hi * 8];
    __syncthreads();   // bq reads done -> stage(1) may clobber Qtmp

    f16v acco0 = {}, acco1 = {};
    float mr = -INFINITY, lr = 0.f;
    const int qg = q0 + w * 32 + l31;          // lane's q row (global)

    for (int kt = 0; kt <= qt; ++kt) {
        const int buf = kt & 1;
        if (kt < qt) stage(kt + 1, buf ^ 1);

        // S^T = K Q^T : rows=keys (2 tiles of 32), col=q=l31
        f16v s0 = {}, s1 = {};
        #pragma unroll
        for (int s = 0; s < 4; ++s) {
            const int ch = (s << 1) + hi;
            const int row0 = l31, row1 = 32 + l31;
            s8v ak0 = *(const s8v*)&Kbuf[buf * 4096 + row0 * 64 + ((ch ^ (row0 & 7)) << 3)];
            s8v ak1 = *(const s8v*)&Kbuf[buf * 4096 + row1 * 64 + ((ch ^ (row1 & 7)) << 3)];
            s0 = __builtin_amdgcn_mfma_f32_32x32x16_bf16(ak0, bq[s], s0, 0, 0, 0);
            s1 = __builtin_amdgcn_mfma_f32_32x32x16_bf16(ak1, bq[s], s1, 0, 0, 0);
        }

        // causal mask (diag tile only) + running max
        float mloc = -INFINITY;
        if (kt == qt) {
            #pragma unroll
            for (int r = 0; r < 16; ++r) {
                const int keyb = kt * 64 + (r & 3) + 8 * (r >> 2) + 4 * hi;
                float v0 = (keyb > qg) ? -INFINITY : s0[r];
                float v1 = (keyb + 32 > qg) ? -INFINITY : s1[r];
                s0[r] = v0; s1[r] = v1;
                mloc = fmaxf(mloc, fmaxf(v0, v1));
            }
        } else {
            #pragma unroll
            for (int r = 0; r < 16; ++r)
                mloc = fmaxf(mloc, fmaxf(s0[r], s1[r]));
        }
        mloc = fmaxf(mloc, __shfl_xor(mloc, 32));
        const float mnew = fmaxf(mr, mloc);
        const float alpha = EXP2F(mr - mnew);
        mr = mnew;

        // exp2 + row sum + bf16 pack (pairs of consecutive keys)
        float ps = 0.f;
        u32 P0[8], P1[8];
        #pragma unroll
        for (int p = 0; p < 8; ++p) {
            float a0 = EXP2F(s0[2 * p] - mnew), b0 = EXP2F(s0[2 * p + 1] - mnew);
            float a1 = EXP2F(s1[2 * p] - mnew), b1 = EXP2F(s1[2 * p + 1] - mnew);
            ps += (a0 + b0) + (a1 + b1);
            P0[p] = bfpack(a0, b0); P1[p] = bfpack(a1, b1);
        }
        ps += __shfl_xor(ps, 32);
        lr = lr * alpha + ps;

        #pragma unroll
        for (int r = 0; r < 16; ++r) { acco0[r] *= alpha; acco1[r] *= alpha; }

        // O^T += V^T P^T.  B-frag(P^T) built in-register: lane half swap.
        #pragma unroll
        for (int t = 0; t < 2; ++t) {
            const u32* pt = t ? P1 : P0;
            #pragma unroll
            for (int ss = 0; ss < 2; ++ss) {
                const int b4 = ss * 4;
                const u32 x0 = __shfl_xor(pt[b4 + 0], 32);
                const u32 x1 = __shfl_xor(pt[b4 + 1], 32);
                const u32 x2 = __shfl_xor(pt[b4 + 2], 32);
                const u32 x3 = __shfl_xor(pt[b4 + 3], 32);
                uint4 fr;
                fr.x = hi ? x2 : pt[b4 + 0];
                fr.y = hi ? x3 : pt[b4 + 1];
                fr.z = hi ? pt[b4 + 2] : x0;
                fr.w = hi ? pt[b4 + 3] : x1;
                const s8v pf = __builtin_bit_cast(s8v, fr);
                const int sg = t * 2 + ss, ch = (sg << 1) + hi;
                const int row0 = l31, row1 = 32 + l31;
                s8v av0 = *(const s8v*)&Vbuf[buf * 4096 + row0 * 64 + ((ch ^ (row0 & 7)) << 3)];
                s8v av1 = *(const s8v*)&Vbuf[buf * 4096 + row1 * 64 + ((ch ^ (row1 & 7)) << 3)];
                acco0 = __builtin_amdgcn_mfma_f32_32x32x16_bf16(av0, pf, acco0, 0, 0, 0);
                acco1 = __builtin_amdgcn_mfma_f32_32x32x16_bf16(av1, pf, acco1, 0, 0, 0);
            }
        }

        __syncthreads();   // waves done with buf; next-tile DMA drained here
    }

    // ---- epilogue: per-wave LDS transpose (overlay K/V) -> coalesced stores
    float* LTw = (float*)SMEM + w * (32 * 68);
    const float inv = 1.0f / lr;
    #pragma unroll
    for (int r = 0; r < 16; ++r) {
        const int d = (r & 3) + 8 * (r >> 2) + 4 * hi;
        LTw[l31 * 68 + d] = acco0[r] * inv;
        LTw[l31 * 68 + 32 + d] = acco1[r] * inv;
    }
    const int qr2 = lane >> 4, chk = lane & 15;
    #pragma unroll
    for (int p = 0; p < 8; ++p) {
        const int qrow = p * 4 + qr2;
        f4v v = *(const f4v*)&LTw[qrow * 68 + chk * 4];
        *(float4*)(Y + (size_t)(b * 2048 + q0 + w * 32 + qrow) * 1024
                   + h * 64 + chk * 4) = (float4){v[0], v[1], v[2], v[3]};
    }
}

// ---------------------------------------------------------------------------
extern "C" void kernel_launch(void* const* d_in, const int* in_sizes, int n_in,
                              void* d_out, int out_size, void* d_ws,
                              size_t ws_size, hipStream_t stream)
{
    const float* x_qk = (const float*)d_in[0];
    const float* x_v  = (const float*)d_in[1];
    const float* W    = (const float*)d_in[2];
    const float* bias = (const float*)d_in[3];
    float* out = (float*)d_out;

    unsigned char* ws = (unsigned char*)d_ws;
    ush* Wt = (ush*)(ws);                  // 4 MB  [0,4M)
    ush* Vt = (ush*)(ws + (4u << 20));     // 8 MB  [4M,12M)
    ush* Qb = (ush*)(ws + (12u << 20));    // 8 MB  [12M,20M)
    ush* Kb = (ush*)(ws + (20u << 20));    // 8 MB  [20M,28M)

    prep_kernel<<<1536, 256, 0, stream>>>(W, x_v, Wt, Vt);
    gemm_kernel<<<dim3(16, 32), 256, 0, stream>>>(x_qk, Wt, bias, Qb, Kb);
    attn_kernel<<<1024, 128, 0, stream>>>(Qb, Kb, Vt, out);
}